// Round 5
// baseline (6599.541 us; speedup 1.0000x reference)
//
#include <hip/hip_runtime.h>

// ============================================================================
// StateSequencePredictor  (B=16384, EMBED=512, STATE=128, HIDDEN=256, T=32)
//
// R3 (2nd resubmit after infra timeouts): attack latency-boundness (R2: all
// pipes <20%, occupancy 24%, 2 waves/SIMD). Halve the block to 32 rows (LDS
// 64KB) -> 2 blocks/CU, 16 waves/CU, 4 waves/SIMD. Per-wave inner code
// identical to R2 (pure ds_read+MFMA inner loop); mt tiles 4->2, acc VGPRs
// 64->32 so the 128-VGPR cap for 4 waves/EU holds.
//
//  * 512 blocks x 512 threads (8 waves); block owns 32 rows, all 32 steps.
//  * LDS 64KB: H0hi|H0lo|H1hi|H1lo, each [32][256] bf16, 16B-granule
//    XOR-swizzle; prologue aliases the same 64KB as [32][512] fp32 emb tile.
//  * 3-term split fp32 emulation: x@W ~= xh@Wh + xl@Wh + xh@Wl (bf16 MFMA).
//  * S (16384x128) in d_ws as bf16 hi/lo planes (block-private rows).
// ============================================================================

#define BTOT    16384
#define EMBED   512
#define STATE   128
#define HIDDEN  256
#define HORIZON 32

#define ROWS_PER_BLK 32
#define MT           (ROWS_PER_BLK / 16)   // 2 M-tiles
#define THREADS      512

typedef __attribute__((ext_vector_type(4))) float f32x4;
typedef __attribute__((ext_vector_type(8))) short s16x8;

#define N_Wp    (HIDDEN*EMBED)
#define N_Wih0  (3*HIDDEN*STATE)
#define N_Whh0  (3*HIDDEN*HIDDEN)
#define N_Wih1  (3*HIDDEN*HIDDEN)
#define N_Whh1  (3*HIDDEN*HIDDEN)
#define N_Wo    (STATE*HIDDEN)
#define OFF_Wp   0
#define OFF_Wih0 (OFF_Wp   + N_Wp)
#define OFF_Whh0 (OFF_Wih0 + N_Wih0)
#define OFF_Wih1 (OFF_Whh0 + N_Whh0)
#define OFF_Whh1 (OFF_Wih1 + N_Wih1)
#define OFF_Wo   (OFF_Whh1 + N_Whh1)
#define N_WTOT   (OFF_Wo   + N_Wo)      // 851968 elements

// ---------------- bf16 helpers (RNE) ----------------
__device__ __forceinline__ short f2bf(float f) {
    unsigned u = __float_as_uint(f);
    u += 0x7FFFu + ((u >> 16) & 1u);
    return (short)(u >> 16);
}
__device__ __forceinline__ float bf2f(short h) {
    return __uint_as_float(((unsigned)(unsigned short)h) << 16);
}
__device__ __forceinline__ void split8(const f32x4 a, const f32x4 b, s16x8 &hi, s16x8 &lo) {
#pragma unroll
    for (int i = 0; i < 4; i++) {
        short h = f2bf(a[i]); hi[i] = h; lo[i] = f2bf(a[i] - bf2f(h));
    }
#pragma unroll
    for (int i = 0; i < 4; i++) {
        short h = f2bf(b[i]); hi[4+i] = h; lo[4+i] = f2bf(b[i] - bf2f(h));
    }
}

// ---- LDS short-plane addressing: [32][256] bf16, 16B-granule XOR swizzle ----
__device__ __forceinline__ int sidx(int row, int col) {
    return row * 256 + ((((col >> 3) ^ (row & 7)) << 3) | (col & 7));
}
__device__ __forceinline__ int sfrag(int row, int k0) {   // k0 multiple of 8
    return row * 256 + (((k0 >> 3) ^ (row & 7)) << 3);
}

// ---- fp32 LDS addressing for the prologue emb tile [32][512] ----
__device__ __forceinline__ int fswz(int row, int col) {
    return row * EMBED + ((((col >> 2) ^ (row & 7)) << 2) | (col & 3));
}
__device__ __forceinline__ void lds_frag_f32(const float* H, int row, int k0,
                                             s16x8 &hi, s16x8 &lo) {
    int base = row * EMBED;
    int s0 = (((k0 >> 2)    ) ^ (row & 7)) << 2;
    int s1 = (((k0 >> 2) + 1) ^ (row & 7)) << 2;
    f32x4 a = *(const f32x4*)(H + base + s0);
    f32x4 b = *(const f32x4*)(H + base + s1);
    split8(a, b, hi, lo);
}

#define MFMA(A, B, C) __builtin_amdgcn_mfma_f32_16x16x32_bf16(A, B, C, 0, 0, 0)

// 3-term split MFMA block for one gate-category (3*MT MFMAs, MT indep chains)
template<int KW>
__device__ __forceinline__ void catblock(f32x4 (&acc)[MT],
                                         const s16x8 (&ahi)[MT], const s16x8 (&alo)[MT],
                                         const short* __restrict__ WHi,
                                         const short* __restrict__ WLo,
                                         int wr, int k0) {
    s16x8 bhi = *(const s16x8*)(WHi + wr * KW + k0);
    s16x8 blo = *(const s16x8*)(WLo + wr * KW + k0);
#pragma unroll
    for (int mt = 0; mt < MT; mt++) acc[mt] = MFMA(ahi[mt], bhi, acc[mt]);
#pragma unroll
    for (int mt = 0; mt < MT; mt++) acc[mt] = MFMA(alo[mt], bhi, acc[mt]);
#pragma unroll
    for (int mt = 0; mt < MT; mt++) acc[mt] = MFMA(ahi[mt], blo, acc[mt]);
}

__device__ __forceinline__ float sigf(float x)  { return 1.0f / (1.0f + __expf(-x)); }
__device__ __forceinline__ float tanhf_(float x){ return 1.0f - 2.0f / (__expf(2.0f * x) + 1.0f); }

// ---------------- one GRU layer (2 passes of 16 gate cols per wave) ----------------
template<int KI, bool AGLOB>
__device__ __forceinline__ void gru_layer(
    const short* __restrict__ AiHi, const short* __restrict__ AiLo,
    const short* __restrict__ HHi,  const short* __restrict__ HLo,
    const short* __restrict__ WihHi, const short* __restrict__ WihLo,
    const short* __restrict__ WhhHi, const short* __restrict__ WhhLo,
    const float br[2], const float bz[2], const float bi[2], const float bh[2],
    int rowbase, int wave, int lr, int lg,
    float hnew[2][MT][4])
{
#pragma unroll
    for (int p = 0; p < 2; p++) {
        f32x4 aR[MT], aZ[MT], aI[MT], aH[MT];
        {
            f32x4 zz = {0.f, 0.f, 0.f, 0.f};
#pragma unroll
            for (int mt = 0; mt < MT; mt++) { aR[mt]=zz; aZ[mt]=zz; aI[mt]=zz; aH[mt]=zz; }
        }
        const int hcol = wave * 32 + p * 16 + lr;
        // ---- gi = x @ Wih^T ----
#pragma unroll 2
        for (int kc = 0; kc < KI / 32; kc++) {
            const int k0 = kc * 32 + lg * 8;
            s16x8 ahi[MT], alo[MT];
#pragma unroll
            for (int mt = 0; mt < MT; mt++) {
                if constexpr (AGLOB) {
                    size_t base = (size_t)(rowbase + mt * 16 + lr) * KI + k0;
                    ahi[mt] = *(const s16x8*)(AiHi + base);
                    alo[mt] = *(const s16x8*)(AiLo + base);
                } else {
                    int off = sfrag(mt * 16 + lr, k0);
                    ahi[mt] = *(const s16x8*)(AiHi + off);
                    alo[mt] = *(const s16x8*)(AiLo + off);
                }
            }
            catblock<KI>(aR, ahi, alo, WihHi, WihLo, 0 * HIDDEN + hcol, k0);
            catblock<KI>(aZ, ahi, alo, WihHi, WihLo, 1 * HIDDEN + hcol, k0);
            catblock<KI>(aI, ahi, alo, WihHi, WihLo, 2 * HIDDEN + hcol, k0);
        }
        // ---- gh = h_old @ Whh^T  (K = 256, from LDS split planes) ----
#pragma unroll 2
        for (int kc = 0; kc < HIDDEN / 32; kc++) {
            const int k0 = kc * 32 + lg * 8;
            s16x8 ahi[MT], alo[MT];
#pragma unroll
            for (int mt = 0; mt < MT; mt++) {
                int off = sfrag(mt * 16 + lr, k0);
                ahi[mt] = *(const s16x8*)(HHi + off);
                alo[mt] = *(const s16x8*)(HLo + off);
            }
            catblock<HIDDEN>(aR, ahi, alo, WhhHi, WhhLo, 0 * HIDDEN + hcol, k0);
            catblock<HIDDEN>(aZ, ahi, alo, WhhHi, WhhLo, 1 * HIDDEN + hcol, k0);
            catblock<HIDDEN>(aH, ahi, alo, WhhHi, WhhLo, 2 * HIDDEN + hcol, k0);
        }
        // ---- elementwise gates (fp32) ----
#pragma unroll
        for (int mt = 0; mt < MT; mt++)
#pragma unroll
            for (int j = 0; j < 4; j++) {
                int row  = mt * 16 + lg * 4 + j;
                float r  = sigf(aR[mt][j] + br[p]);
                float z  = sigf(aZ[mt][j] + bz[p]);
                float n  = tanhf_(aI[mt][j] + bi[p] + r * (aH[mt][j] + bh[p]));
                float ho = bf2f(HHi[sidx(row, hcol)]) + bf2f(HLo[sidx(row, hcol)]);
                hnew[p][mt][j] = (1.0f - z) * n + z * ho;
            }
    }
}

__device__ __forceinline__ void write_h(short* HHi, short* HLo, const float hnew[2][MT][4],
                                        int wave, int lr, int lg) {
#pragma unroll
    for (int p = 0; p < 2; p++) {
        int col = wave * 32 + p * 16 + lr;
#pragma unroll
        for (int mt = 0; mt < MT; mt++)
#pragma unroll
            for (int j = 0; j < 4; j++) {
                int row = mt * 16 + lg * 4 + j;
                float v = hnew[p][mt][j];
                short hi = f2bf(v);
                short lo = f2bf(v - bf2f(hi));
                HHi[sidx(row, col)] = hi;
                HLo[sidx(row, col)] = lo;
            }
    }
}

// ---------------- prep: split weights ----------------
__global__ void prep_split(const float* __restrict__ Wp,   const float* __restrict__ Wih0,
                           const float* __restrict__ Whh0, const float* __restrict__ Wih1,
                           const float* __restrict__ Whh1, const float* __restrict__ Wo,
                           short* __restrict__ hi, short* __restrict__ lo) {
    int i = blockIdx.x * 256 + threadIdx.x;
    if (i >= N_WTOT) return;
    float w;
    if      (i < OFF_Wih0) w = Wp  [i - OFF_Wp];
    else if (i < OFF_Whh0) w = Wih0[i - OFF_Wih0];
    else if (i < OFF_Wih1) w = Whh0[i - OFF_Whh0];
    else if (i < OFF_Whh1) w = Wih1[i - OFF_Wih1];
    else if (i < OFF_Wo)   w = Whh1[i - OFF_Whh1];
    else                   w = Wo  [i - OFF_Wo];
    short h = f2bf(w);
    hi[i] = h;
    lo[i] = f2bf(w - bf2f(h));
}

// ---------------- prep: split initial_state into S planes ----------------
__global__ void prep_state(const float* __restrict__ s0,
                           short* __restrict__ shi, short* __restrict__ slo) {
    int i = blockIdx.x * 256 + threadIdx.x;
    if (i >= BTOT * STATE) return;
    float w = s0[i];
    short h = f2bf(w);
    shi[i] = h;
    slo[i] = f2bf(w - bf2f(h));
}

// ---------------- persistent GRU kernel ----------------
__global__ __launch_bounds__(THREADS, 4)     // 4 waves/EU -> 2 blocks/CU, VGPR<=128
void gru_main(const float* __restrict__ emb,
              const float* __restrict__ bp,
              const float* __restrict__ bih0, const float* __restrict__ bhh0,
              const float* __restrict__ bih1, const float* __restrict__ bhh1,
              const float* __restrict__ bo,
              const short* __restrict__ Whi,  const short* __restrict__ Wlo,
              short* __restrict__ Shi, short* __restrict__ Slo,
              float* __restrict__ out) {
    __shared__ short sH[4 * ROWS_PER_BLK * HIDDEN];     // 64 KiB
    short* H0hi = sH;
    short* H0lo = sH + 1 * ROWS_PER_BLK * HIDDEN;
    short* H1hi = sH + 2 * ROWS_PER_BLK * HIDDEN;
    short* H1lo = sH + 3 * ROWS_PER_BLK * HIDDEN;
    float* fl   = (float*)sH;                            // prologue alias [32][512]

    const int tid  = threadIdx.x;
    const int wave = tid >> 6, lane = tid & 63;
    const int lr = lane & 15, lg = lane >> 4;
    const int rowbase = blockIdx.x * ROWS_PER_BLK;

    const short *WpHi   = Whi + OFF_Wp,   *WpLo   = Wlo + OFF_Wp;
    const short *Wih0Hi = Whi + OFF_Wih0, *Wih0Lo = Wlo + OFF_Wih0;
    const short *Whh0Hi = Whi + OFF_Whh0, *Whh0Lo = Wlo + OFF_Whh0;
    const short *Wih1Hi = Whi + OFF_Wih1, *Wih1Lo = Wlo + OFF_Wih1;
    const short *Whh1Hi = Whi + OFF_Whh1, *Whh1Lo = Wlo + OFF_Whh1;
    const short *WoHi   = Whi + OFF_Wo,   *WoLo   = Wlo + OFF_Wo;

    // ---- per-lane bias registers (fixed across steps) ----
    float br0[2], bz0[2], bi0[2], bh0[2];
    float br1[2], bz1[2], bi1[2], bh1[2];
#pragma unroll
    for (int p = 0; p < 2; p++) {
        int c = wave * 32 + p * 16 + lr;
        br0[p] = bih0[c] + bhh0[c];
        bz0[p] = bih0[HIDDEN + c] + bhh0[HIDDEN + c];
        bi0[p] = bih0[2 * HIDDEN + c];
        bh0[p] = bhh0[2 * HIDDEN + c];
        br1[p] = bih1[c] + bhh1[c];
        bz1[p] = bih1[HIDDEN + c] + bhh1[HIDDEN + c];
        bi1[p] = bih1[2 * HIDDEN + c];
        bh1[p] = bhh1[2 * HIDDEN + c];
    }
    const int scol = wave * 16 + lr;
    const float bo_v = bo[scol];
    float bpv[2];
    bpv[0] = bp[wave * 32 + lr];
    bpv[1] = bp[wave * 32 + 16 + lr];

    // ===== prologue: h_init = emb @ Wp^T + bp (emb fp32 tile in the 64KB) =====
    for (int idx = tid; idx < ROWS_PER_BLK * EMBED; idx += THREADS) {
        int r = idx >> 9, c = idx & (EMBED - 1);
        fl[fswz(r, c)] = emb[(size_t)(rowbase + r) * EMBED + c];
    }
    __syncthreads();
    f32x4 hacc[2][MT];
    {
        f32x4 zz = {0.f, 0.f, 0.f, 0.f};
#pragma unroll
        for (int nt = 0; nt < 2; nt++)
#pragma unroll
            for (int mt = 0; mt < MT; mt++) hacc[nt][mt] = zz;
    }
#pragma unroll 2
    for (int kc = 0; kc < EMBED / 32; kc++) {
        const int k0 = kc * 32 + lg * 8;
        s16x8 ahi[MT], alo[MT];
#pragma unroll
        for (int mt = 0; mt < MT; mt++)
            lds_frag_f32(fl, mt * 16 + lr, k0, ahi[mt], alo[mt]);
#pragma unroll
        for (int nt = 0; nt < 2; nt++)
            catblock<EMBED>(hacc[nt], ahi, alo, WpHi, WpLo, wave * 32 + nt * 16 + lr, k0);
    }
    __syncthreads();   // emb reads done before overwriting LDS with H planes
#pragma unroll
    for (int nt = 0; nt < 2; nt++)
#pragma unroll
        for (int mt = 0; mt < MT; mt++)
#pragma unroll
            for (int j = 0; j < 4; j++) {
                int row = mt * 16 + lg * 4 + j;
                int col = wave * 32 + nt * 16 + lr;
                float v = hacc[nt][mt][j] + bpv[nt];
                short hi = f2bf(v);
                short lo = f2bf(v - bf2f(hi));
                H0hi[sidx(row, col)] = hi;  H0lo[sidx(row, col)] = lo;
                H1hi[sidx(row, col)] = hi;  H1lo[sidx(row, col)] = lo;
            }
    __syncthreads();

    // ===== 32 recurrent steps =====
#pragma unroll 1
    for (int t = 0; t < HORIZON; t++) {
        float hn0[2][MT][4];
        gru_layer<STATE, true>(Shi, Slo, H0hi, H0lo,
                               Wih0Hi, Wih0Lo, Whh0Hi, Whh0Lo,
                               br0, bz0, bi0, bh0,
                               rowbase, wave, lr, lg, hn0);
        __syncthreads();                 // all reads of old H0 done
        write_h(H0hi, H0lo, hn0, wave, lr, lg);
        __syncthreads();                 // new H0 visible

        float hn1[2][MT][4];
        gru_layer<HIDDEN, false>(H0hi, H0lo, H1hi, H1lo,
                                 Wih1Hi, Wih1Lo, Whh1Hi, Whh1Lo,
                                 br1, bz1, bi1, bh1,
                                 rowbase, wave, lr, lg, hn1);
        __syncthreads();                 // all reads of old H1 done
        write_h(H1hi, H1lo, hn1, wave, lr, lg);
        __syncthreads();                 // new H1 visible

        // ---- next_state = h1 @ Wo^T + bo ; emit out[:,t,:] and S planes ----
        f32x4 o[MT];
        {
            f32x4 zz = {0.f, 0.f, 0.f, 0.f};
#pragma unroll
            for (int mt = 0; mt < MT; mt++) o[mt] = zz;
        }
#pragma unroll 2
        for (int kc = 0; kc < HIDDEN / 32; kc++) {
            const int k0 = kc * 32 + lg * 8;
            s16x8 ahi[MT], alo[MT];
#pragma unroll
            for (int mt = 0; mt < MT; mt++) {
                int off = sfrag(mt * 16 + lr, k0);
                ahi[mt] = *(const s16x8*)(H1hi + off);
                alo[mt] = *(const s16x8*)(H1lo + off);
            }
            catblock<HIDDEN>(o, ahi, alo, WoHi, WoLo, scol, k0);
        }
#pragma unroll
        for (int mt = 0; mt < MT; mt++)
#pragma unroll
            for (int j = 0; j < 4; j++) {
                int row   = mt * 16 + lg * 4 + j;
                size_t gr = (size_t)(rowbase + row);
                float v   = o[mt][j] + bo_v;
                out[gr * (size_t)(HORIZON * STATE) + (size_t)t * STATE + scol] = v;
                short hi = f2bf(v);
                short lo = f2bf(v - bf2f(hi));
                Shi[gr * STATE + scol] = hi;
                Slo[gr * STATE + scol] = lo;
            }
        __threadfence_block();   // S plane writes visible to next step's reads
        __syncthreads();
    }
}

extern "C" void kernel_launch(void* const* d_in, const int* in_sizes, int n_in,
                              void* d_out, int out_size, void* d_ws, size_t ws_size,
                              hipStream_t stream) {
    (void)in_sizes; (void)n_in; (void)out_size; (void)ws_size;
    const float* emb  = (const float*)d_in[0];
    const float* st0  = (const float*)d_in[1];
    const float* Wp   = (const float*)d_in[2];
    const float* bp   = (const float*)d_in[3];
    const float* Wih0 = (const float*)d_in[4];
    const float* Whh0 = (const float*)d_in[5];
    const float* bih0 = (const float*)d_in[6];
    const float* bhh0 = (const float*)d_in[7];
    const float* Wih1 = (const float*)d_in[8];
    const float* Whh1 = (const float*)d_in[9];
    const float* bih1 = (const float*)d_in[10];
    const float* bhh1 = (const float*)d_in[11];
    const float* Wo   = (const float*)d_in[12];
    const float* bo   = (const float*)d_in[13];
    float* out = (float*)d_out;

    // d_ws layout: [ Shi 4MB | Slo 4MB | Whi | Wlo ]  (bf16 planes)
    short* shi = (short*)d_ws;
    short* slo = shi + (size_t)BTOT * STATE;
    short* whi = slo + (size_t)BTOT * STATE;
    short* wlo = whi + N_WTOT;

    prep_split<<<(N_WTOT + 255) / 256, 256, 0, stream>>>(Wp, Wih0, Whh0, Wih1, Whh1, Wo, whi, wlo);
    prep_state<<<(BTOT * STATE + 255) / 256, 256, 0, stream>>>(st0, shi, slo);
    gru_main<<<BTOT / ROWS_PER_BLK, THREADS, 0, stream>>>(
        emb, bp, bih0, bhh0, bih1, bhh1, bo, whi, wlo, shi, slo, out);
}